// Round 6
// baseline (246.702 us; speedup 1.0000x reference)
//
#include <hip/hip_runtime.h>
#include <math.h>

#define DMODEL 1024
#define NHEAD  16
#define HDK    64
#define BATCH  2
#define SEQ    2048
#define MROWS  (BATCH*SEQ)   // 4096
#define NQKV   (3*DMODEL)    // 3072
#define LOG2_10000 13.287712379549449f
#define INV2PI 0.15915494309189535f
#define SCALE_LOG2E 0.1803368801111137f   // 0.125 * log2(e)
#define M_FIX 8.0f                        // fixed softmax max (log2 domain)

typedef __attribute__((ext_vector_type(8))) short bf16x8;
typedef __attribute__((ext_vector_type(4))) float f32x4;

__device__ __forceinline__ short f2bf(float f) {
    union { float f; unsigned u; } v; v.f = f;
    unsigned r = v.u + 0x7fffu + ((v.u >> 16) & 1u);
    return (short)(r >> 16);
}

__device__ __forceinline__ float fast_exp2(float x) {
#if __has_builtin(__builtin_amdgcn_exp2f)
    return __builtin_amdgcn_exp2f(x);
#else
    return exp2f(x);
#endif
}

// async global->LDS, 16B per lane; LDS base wave-uniform, HW adds lane*16
__device__ __forceinline__ void gld_lds16(const short* g, short* l) {
    __builtin_amdgcn_global_load_lds(
        (const __attribute__((address_space(1))) void*)g,
        (__attribute__((address_space(3))) void*)l, 16, 0, 0);
}

// ---------------------------------------------------------------------------
// fp32 -> bf16 elementwise
// ---------------------------------------------------------------------------
__global__ __launch_bounds__(256) void convert_kernel(
    const float* __restrict__ in, short* __restrict__ out, int n)
{
    int i = (blockIdx.x * 256 + threadIdx.x) * 8;
    if (i >= n) return;
    float4 a = *(const float4*)(in + i);
    float4 b = *(const float4*)(in + i + 4);
    bf16x8 o;
    o[0] = f2bf(a.x); o[1] = f2bf(a.y); o[2] = f2bf(a.z); o[3] = f2bf(a.w);
    o[4] = f2bf(b.x); o[5] = f2bf(b.y); o[6] = f2bf(b.z); o[7] = f2bf(b.w);
    *(bf16x8*)(out + i) = o;
}

// ---------------------------------------------------------------------------
// Both weights fp32 (K,N) -> bf16 (N,K) in one launch.
// grid ((96+32), 32), block (32,8). bx<96 -> W_qkv, else W_out.
// ---------------------------------------------------------------------------
__global__ __launch_bounds__(256) void transpose_both_kernel(
    const float* __restrict__ wqkv, const float* __restrict__ wout,
    short* __restrict__ wqkv_t, short* __restrict__ wout_t)
{
    __shared__ short tile[32][33];
    const int tx = threadIdx.x, ty = threadIdx.y;
    int bx = blockIdx.x;
    const float* in; short* out; int N;
    if (bx < 96) { in = wqkv; out = wqkv_t; N = NQKV; }
    else         { in = wout; out = wout_t; N = DMODEL; bx -= 96; }
    const int n0 = bx * 32, k0 = blockIdx.y * 32;
    #pragma unroll
    for (int i = 0; i < 32; i += 8)
        tile[ty + i][tx] = f2bf(in[(size_t)(k0 + ty + i) * N + n0 + tx]);
    __syncthreads();
    #pragma unroll
    for (int i = 0; i < 32; i += 8)
        out[(size_t)(n0 + ty + i) * DMODEL + k0 + tx] = tile[tx][ty + i];
}

// ---------------------------------------------------------------------------
// QKV GEMM: MFMA bf16, global_load_lds, k-major LDS, DOUBLE-BUFFERED with raw
// s_waitcnt vmcnt(4)/s_barrier so the prefetch stays in flight across the
// barrier (m139 pattern). + bias + RoPE + scatter; V stored transposed.
// ---------------------------------------------------------------------------
__global__ __launch_bounds__(256) void qkv_gemm_kernel(
    const short* __restrict__ xb, const short* __restrict__ Wt,
    const float* __restrict__ bias,
    short* __restrict__ qd, short* __restrict__ kd, short* __restrict__ vtb)
{
    __shared__ __align__(16) short As[2][4096];   // [buf][kc(4)][row(128)][8]
    __shared__ __align__(16) short Bs[2][4096];
    const int tid = threadIdx.x;
    const int lane = tid & 63, wave = tid >> 6;
    const int wm = wave & 1, wn = wave >> 1;
    const int l15 = lane & 15, quad = lane >> 4;
    const int n0 = blockIdx.x * 128, m0 = blockIdx.y * 128;

    const short* gA1 = xb + (size_t)(m0 + lane) * DMODEL + wave * 8;
    const short* gA2 = xb + (size_t)(m0 + 64 + lane) * DMODEL + wave * 8;
    const short* gB1 = Wt + (size_t)(n0 + lane) * DMODEL + wave * 8;
    const short* gB2 = Wt + (size_t)(n0 + 64 + lane) * DMODEL + wave * 8;
    const int lof1 = wave * 1024, lof2 = wave * 1024 + 512;

    f32x4 zero = {0.f, 0.f, 0.f, 0.f};
    f32x4 acc[4][4];
    #pragma unroll
    for (int i = 0; i < 4; ++i)
        #pragma unroll
        for (int j = 0; j < 4; ++j) acc[i][j] = zero;

    // prologue: stage tile 0 into buf 0
    gld_lds16(gA1, &As[0][lof1]); gld_lds16(gA2, &As[0][lof2]);
    gld_lds16(gB1, &Bs[0][lof1]); gld_lds16(gB2, &Bs[0][lof2]);

    #pragma unroll 2
    for (int it = 0; it < DMODEL / 32; ++it) {
        const int cur = it & 1;
        const int k1 = (it + 1) * 32;
        if (k1 < DMODEL) {
            gld_lds16(gA1 + k1, &As[cur ^ 1][lof1]);
            gld_lds16(gA2 + k1, &As[cur ^ 1][lof2]);
            gld_lds16(gB1 + k1, &Bs[cur ^ 1][lof1]);
            gld_lds16(gB2 + k1, &Bs[cur ^ 1][lof2]);
            asm volatile("s_waitcnt vmcnt(4)" ::: "memory");
        } else {
            asm volatile("s_waitcnt vmcnt(0)" ::: "memory");
        }
        __builtin_amdgcn_s_barrier();   // cur tile landed for all waves
        bf16x8 af[4], bfr[4];
        #pragma unroll
        for (int i = 0; i < 4; ++i)
            af[i] = *(const bf16x8*)&As[cur][(quad * 128 + wm * 64 + i * 16 + l15) * 8];
        #pragma unroll
        for (int j = 0; j < 4; ++j)
            bfr[j] = *(const bf16x8*)&Bs[cur][(quad * 128 + wn * 64 + j * 16 + l15) * 8];
        #pragma unroll
        for (int i = 0; i < 4; ++i)
            #pragma unroll
            for (int j = 0; j < 4; ++j)
                acc[i][j] = __builtin_amdgcn_mfma_f32_16x16x32_bf16(af[i], bfr[j], acc[i][j], 0, 0, 0);
        asm volatile("" ::: "memory");
        __builtin_amdgcn_s_barrier();   // all waves done reading cur before it's overwritten
    }

    const int which = n0 >> 10;
    float biasv[4], invf[4];
    int hh[4], dd[4];
    #pragma unroll
    for (int j = 0; j < 4; ++j) {
        const int n = n0 + wn * 64 + j * 16 + l15;
        biasv[j] = bias[n];
        hh[j] = (n & 1023) >> 6;
        dd[j] = n & 63;
        invf[j] = INV2PI * exp2f(-((float)(dd[j] & ~1) / 64.f) * LOG2_10000);
    }
    #pragma unroll
    for (int i = 0; i < 4; ++i) {
        #pragma unroll
        for (int r = 0; r < 4; ++r) {
            const int m = m0 + wm * 64 + i * 16 + quad * 4 + r;
            const int b = m >> 11, t = m & (SEQ - 1);
            #pragma unroll
            for (int j = 0; j < 4; ++j) {
                float val = acc[i][j][r] + biasv[j];
                if (which < 2) {
                    const float rev = (float)t * invf[j];
                    const float fr = rev - floorf(rev);
                    const float s = __builtin_amdgcn_sinf(fr);
                    const float c = __builtin_amdgcn_cosf(fr);
                    const float partner = __shfl_xor(val, 1);
                    val = (lane & 1) ? (partner * s + val * c) : (val * c - partner * s);
                    short* dst = (which == 0) ? qd : kd;
                    dst[((size_t)(b * NHEAD + hh[j]) * SEQ + t) * HDK + dd[j]] = f2bf(val);
                } else {
                    vtb[((size_t)(b * NHEAD + hh[j]) * HDK + dd[j]) * SEQ + t] = f2bf(val);
                }
            }
        }
    }
}

// ---------------------------------------------------------------------------
// Flash attention (MFMA bf16), paired Q-tiles (i, 31-i), fixed softmax max,
// REGISTER-PREFETCHED K/V staging (next tile's loads issued before compute).
// grid (16, NHEAD, BATCH), 256 thr = 4 waves.
// ---------------------------------------------------------------------------
__global__ __launch_bounds__(256) void attn_mfma_kernel(
    const short* __restrict__ qd, const short* __restrict__ kd,
    const short* __restrict__ vt, short* __restrict__ od)
{
    __shared__ __align__(16) short Ks[64][72];
    __shared__ __align__(16) short Vs[64][72];     // Vs[d][s]
    __shared__ __align__(16) short Ps[4][16][72];  // per-wave P tile
    const int tid = threadIdx.x, lane = tid & 63, w = tid >> 6;
    const int l15 = lane & 15, quad = lane >> 4;
    const int h = blockIdx.y, b = blockIdx.z;
    const size_t base = ((size_t)(b * NHEAD + h)) * SEQ * HDK;
    const int srow = tid >> 2, sdh = (tid & 3) * 16;
    f32x4 zero = {0.f, 0.f, 0.f, 0.f};

    const int qtile[2] = { (int)blockIdx.x, 31 - (int)blockIdx.x };
    const short* kp = kd + base + (size_t)srow * HDK + sdh;   // tile 0
    const short* vp = vt + base + (size_t)srow * SEQ + sdh;

    #pragma unroll 1
    for (int qi = 0; qi < 2; ++qi) {
        const int q0 = qtile[qi] * 64;
        bf16x8 qf[2];
        {
            const short* qrow = qd + base + (size_t)(q0 + w * 16 + l15) * HDK;
            qf[0] = *(const bf16x8*)(qrow + quad * 8);
            qf[1] = *(const bf16x8*)(qrow + 32 + quad * 8);
        }
        float l_acc[4] = {0.f, 0.f, 0.f, 0.f};
        f32x4 o[4];
        #pragma unroll
        for (int j = 0; j < 4; ++j) o[j] = zero;

        // preload tile 0 of this q-tile pass
        bf16x8 k0v = *(const bf16x8*)kp,       k1v = *(const bf16x8*)(kp + 8);
        bf16x8 v0v = *(const bf16x8*)vp,       v1v = *(const bf16x8*)(vp + 8);

        const int nkt = q0 / 64 + 1;
        for (int kt = 0; kt < nkt; ++kt) {
            __syncthreads();              // prev compute done with Ks/Vs
            *(bf16x8*)&Ks[srow][sdh] = k0v; *(bf16x8*)&Ks[srow][sdh + 8] = k1v;
            *(bf16x8*)&Vs[srow][sdh] = v0v; *(bf16x8*)&Vs[srow][sdh + 8] = v1v;
            __syncthreads();
            // issue next tile's loads NOW so latency overlaps compute
            if (kt + 1 < nkt) {
                const short* kn = kd + base + (size_t)((kt + 1) * 64 + srow) * HDK + sdh;
                const short* vn = vt + base + (size_t)srow * SEQ + (kt + 1) * 64 + sdh;
                k0v = *(const bf16x8*)kn; k1v = *(const bf16x8*)(kn + 8);
                v0v = *(const bf16x8*)vn; v1v = *(const bf16x8*)(vn + 8);
            } else if (qi == 0) {
                // preload tile 0 for the partner q-tile
                k0v = *(const bf16x8*)kp; k1v = *(const bf16x8*)(kp + 8);
                v0v = *(const bf16x8*)vp; v1v = *(const bf16x8*)(vp + 8);
            }

            f32x4 sacc[4];
            #pragma unroll
            for (int j = 0; j < 4; ++j) {
                bf16x8 kf0 = *(const bf16x8*)&Ks[j * 16 + l15][quad * 8];
                bf16x8 kf1 = *(const bf16x8*)&Ks[j * 16 + l15][32 + quad * 8];
                sacc[j] = __builtin_amdgcn_mfma_f32_16x16x32_bf16(qf[0], kf0, zero, 0, 0, 0);
                sacc[j] = __builtin_amdgcn_mfma_f32_16x16x32_bf16(qf[1], kf1, sacc[j], 0, 0, 0);
            }
            if (kt == nkt - 1) {                   // diagonal tile: mask
                const int s0 = kt * 64;
                #pragma unroll
                for (int j = 0; j < 4; ++j) {
                    const int scol = s0 + j * 16 + l15;
                    #pragma unroll
                    for (int r = 0; r < 4; ++r) {
                        const int trow = q0 + w * 16 + quad * 4 + r;
                        const float sv = sacc[j][r] * SCALE_LOG2E - M_FIX;
                        const float p = (scol > trow) ? 0.f : fast_exp2(sv);
                        l_acc[r] += p;
                        Ps[w][quad * 4 + r][j * 16 + l15] = f2bf(p);
                    }
                }
            } else {
                #pragma unroll
                for (int j = 0; j < 4; ++j)
                    #pragma unroll
                    for (int r = 0; r < 4; ++r) {
                        const float p = fast_exp2(sacc[j][r] * SCALE_LOG2E - M_FIX);
                        l_acc[r] += p;
                        Ps[w][quad * 4 + r][j * 16 + l15] = f2bf(p);
                    }
            }
            bf16x8 pf0 = *(const bf16x8*)&Ps[w][l15][quad * 8];
            bf16x8 pf1 = *(const bf16x8*)&Ps[w][l15][32 + quad * 8];
            #pragma unroll
            for (int j = 0; j < 4; ++j) {
                bf16x8 vf0 = *(const bf16x8*)&Vs[j * 16 + l15][quad * 8];
                bf16x8 vf1 = *(const bf16x8*)&Vs[j * 16 + l15][32 + quad * 8];
                o[j] = __builtin_amdgcn_mfma_f32_16x16x32_bf16(pf0, vf0, o[j], 0, 0, 0);
                o[j] = __builtin_amdgcn_mfma_f32_16x16x32_bf16(pf1, vf1, o[j], 0, 0, 0);
            }
        }

        #pragma unroll
        for (int r = 0; r < 4; ++r) {
            float sr = l_acc[r];
            #pragma unroll
            for (int off = 1; off < 16; off <<= 1) sr += __shfl_xor(sr, off);
            l_acc[r] = sr;
        }
        #pragma unroll
        for (int r = 0; r < 4; ++r) {
            const float inv = 1.f / l_acc[r];
            const int t = q0 + w * 16 + quad * 4 + r;
            #pragma unroll
            for (int j = 0; j < 4; ++j)
                od[((size_t)(b * SEQ + t) * NHEAD + h) * HDK + j * 16 + l15] =
                    f2bf(o[j][r] * inv);
        }
    }
}

// ---------------------------------------------------------------------------
// Output GEMM: same dbuf structure as qkv. out = attn @ W_out + b (fp32)
// ---------------------------------------------------------------------------
__global__ __launch_bounds__(256) void out_gemm_kernel(
    const short* __restrict__ Ab, const short* __restrict__ Wt,
    const float* __restrict__ bias, float* __restrict__ out)
{
    __shared__ __align__(16) short As[2][4096];
    __shared__ __align__(16) short Bs[2][4096];
    const int tid = threadIdx.x;
    const int lane = tid & 63, wave = tid >> 6;
    const int wm = wave & 1, wn = wave >> 1;
    const int l15 = lane & 15, quad = lane >> 4;
    const int n0 = blockIdx.x * 128, m0 = blockIdx.y * 128;

    const short* gA1 = Ab + (size_t)(m0 + lane) * DMODEL + wave * 8;
    const short* gA2 = Ab + (size_t)(m0 + 64 + lane) * DMODEL + wave * 8;
    const short* gB1 = Wt + (size_t)(n0 + lane) * DMODEL + wave * 8;
    const short* gB2 = Wt + (size_t)(n0 + 64 + lane) * DMODEL + wave * 8;
    const int lof1 = wave * 1024, lof2 = wave * 1024 + 512;

    f32x4 zero = {0.f, 0.f, 0.f, 0.f};
    f32x4 acc[4][4];
    #pragma unroll
    for (int i = 0; i < 4; ++i)
        #pragma unroll
        for (int j = 0; j < 4; ++j) acc[i][j] = zero;

    gld_lds16(gA1, &As[0][lof1]); gld_lds16(gA2, &As[0][lof2]);
    gld_lds16(gB1, &Bs[0][lof1]); gld_lds16(gB2, &Bs[0][lof2]);

    #pragma unroll 2
    for (int it = 0; it < DMODEL / 32; ++it) {
        const int cur = it & 1;
        const int k1 = (it + 1) * 32;
        if (k1 < DMODEL) {
            gld_lds16(gA1 + k1, &As[cur ^ 1][lof1]);
            gld_lds16(gA2 + k1, &As[cur ^ 1][lof2]);
            gld_lds16(gB1 + k1, &Bs[cur ^ 1][lof1]);
            gld_lds16(gB2 + k1, &Bs[cur ^ 1][lof2]);
            asm volatile("s_waitcnt vmcnt(4)" ::: "memory");
        } else {
            asm volatile("s_waitcnt vmcnt(0)" ::: "memory");
        }
        __builtin_amdgcn_s_barrier();
        bf16x8 af[4], bfr[4];
        #pragma unroll
        for (int i = 0; i < 4; ++i)
            af[i] = *(const bf16x8*)&As[cur][(quad * 128 + wm * 64 + i * 16 + l15) * 8];
        #pragma unroll
        for (int j = 0; j < 4; ++j)
            bfr[j] = *(const bf16x8*)&Bs[cur][(quad * 128 + wn * 64 + j * 16 + l15) * 8];
        #pragma unroll
        for (int i = 0; i < 4; ++i)
            #pragma unroll
            for (int j = 0; j < 4; ++j)
                acc[i][j] = __builtin_amdgcn_mfma_f32_16x16x32_bf16(af[i], bfr[j], acc[i][j], 0, 0, 0);
        asm volatile("" ::: "memory");
        __builtin_amdgcn_s_barrier();
    }

    #pragma unroll
    for (int j = 0; j < 4; ++j) {
        const int n = n0 + wn * 64 + j * 16 + l15;
        const float bv = bias[n];
        #pragma unroll
        for (int i = 0; i < 4; ++i)
            #pragma unroll
            for (int r = 0; r < 4; ++r) {
                const int m = m0 + wm * 64 + i * 16 + quad * 4 + r;
                out[(size_t)m * DMODEL + n] = acc[i][j][r] + bv;
            }
    }
}

// ---------------------------------------------------------------------------
extern "C" void kernel_launch(void* const* d_in, const int* in_sizes, int n_in,
                              void* d_out, int out_size, void* d_ws, size_t ws_size,
                              hipStream_t stream) {
    const float* x    = (const float*)d_in[0];
    const float* Wqkv = (const float*)d_in[1];
    const float* bqkv = (const float*)d_in[2];
    const float* Wout = (const float*)d_in[3];
    const float* bout = (const float*)d_in[4];
    float* out = (float*)d_out;

    short* ws = (short*)d_ws;
    short* xb     = ws;                                // 4M elems
    short* wqkv_t = xb + (size_t)4 * 1024 * 1024;      // 3M
    short* wout_t = wqkv_t + (size_t)3 * 1024 * 1024;  // 1M
    short* qd     = wout_t + (size_t)1024 * 1024;      // 4M
    short* kd     = qd + (size_t)4 * 1024 * 1024;      // 4M
    short* vtb    = kd + (size_t)4 * 1024 * 1024;      // 4M (transposed V)
    short* attn   = vtb + (size_t)4 * 1024 * 1024;     // 4M  (total 48 MB)

    convert_kernel<<<(MROWS * DMODEL) / (256 * 8), 256, 0, stream>>>(
        x, xb, MROWS * DMODEL);
    transpose_both_kernel<<<dim3(96 + 32, 32), dim3(32, 8), 0, stream>>>(
        Wqkv, Wout, wqkv_t, wout_t);

    qkv_gemm_kernel<<<dim3(NQKV / 128, MROWS / 128), 256, 0, stream>>>(
        xb, wqkv_t, bqkv, qd, kd, vtb);

    attn_mfma_kernel<<<dim3(16, NHEAD, BATCH), 256, 0, stream>>>(
        qd, kd, vtb, attn);

    out_gemm_kernel<<<dim3(DMODEL / 128, MROWS / 128), 256, 0, stream>>>(
        attn, wout_t, bout, out);
}

// Round 7
// 197.820 us; speedup vs baseline: 1.2471x; 1.2471x over previous
//
#include <hip/hip_runtime.h>
#include <math.h>

#define DMODEL 1024
#define NHEAD  16
#define HDK    64
#define BATCH  2
#define SEQ    2048
#define MROWS  (BATCH*SEQ)   // 4096
#define NQKV   (3*DMODEL)    // 3072
#define LOG2_10000 13.287712379549449f
#define INV2PI 0.15915494309189535f
#define SCALE_LOG2E 0.1803368801111137f   // 0.125 * log2(e)
#define M_FIX 8.0f                        // fixed softmax max (log2 domain)

typedef __attribute__((ext_vector_type(8))) short bf16x8;
typedef __attribute__((ext_vector_type(4))) float f32x4;

__device__ __forceinline__ short f2bf(float f) {
    union { float f; unsigned u; } v; v.f = f;
    unsigned r = v.u + 0x7fffu + ((v.u >> 16) & 1u);
    return (short)(r >> 16);
}

__device__ __forceinline__ float fast_exp2(float x) {
#if __has_builtin(__builtin_amdgcn_exp2f)
    return __builtin_amdgcn_exp2f(x);
#else
    return exp2f(x);
#endif
}

// async global->LDS, 16B per lane; LDS base wave-uniform, HW adds lane*16
__device__ __forceinline__ void gld_lds16(const short* g, short* l) {
    __builtin_amdgcn_global_load_lds(
        (const __attribute__((address_space(1))) void*)g,
        (__attribute__((address_space(3))) void*)l, 16, 0, 0);
}

// ---------------------------------------------------------------------------
// fp32 -> bf16 elementwise
// ---------------------------------------------------------------------------
__global__ __launch_bounds__(256) void convert_kernel(
    const float* __restrict__ in, short* __restrict__ out, int n)
{
    int i = (blockIdx.x * 256 + threadIdx.x) * 8;
    if (i >= n) return;
    float4 a = *(const float4*)(in + i);
    float4 b = *(const float4*)(in + i + 4);
    bf16x8 o;
    o[0] = f2bf(a.x); o[1] = f2bf(a.y); o[2] = f2bf(a.z); o[3] = f2bf(a.w);
    o[4] = f2bf(b.x); o[5] = f2bf(b.y); o[6] = f2bf(b.z); o[7] = f2bf(b.w);
    *(bf16x8*)(out + i) = o;
}

// ---------------------------------------------------------------------------
// Both weights fp32 (K,N) -> bf16 (N,K) in one launch.
// grid ((96+32), 32), block (32,8). bx<96 -> W_qkv, else W_out.
// ---------------------------------------------------------------------------
__global__ __launch_bounds__(256) void transpose_both_kernel(
    const float* __restrict__ wqkv, const float* __restrict__ wout,
    short* __restrict__ wqkv_t, short* __restrict__ wout_t)
{
    __shared__ short tile[32][33];
    const int tx = threadIdx.x, ty = threadIdx.y;
    int bx = blockIdx.x;
    const float* in; short* out; int N;
    if (bx < 96) { in = wqkv; out = wqkv_t; N = NQKV; }
    else         { in = wout; out = wout_t; N = DMODEL; bx -= 96; }
    const int n0 = bx * 32, k0 = blockIdx.y * 32;
    #pragma unroll
    for (int i = 0; i < 32; i += 8)
        tile[ty + i][tx] = f2bf(in[(size_t)(k0 + ty + i) * N + n0 + tx]);
    __syncthreads();
    #pragma unroll
    for (int i = 0; i < 32; i += 8)
        out[(size_t)(n0 + ty + i) * DMODEL + k0 + tx] = tile[tx][ty + i];
}

// ---------------------------------------------------------------------------
// QKV GEMM (MFMA bf16, global_load_lds, ROW-MAJOR LDS [128][32]):
// staging lane -> (row = lane>>2, kchunk = lane&3): 16 full 64B lines/instr,
// LDS dst lane-consecutive; frag reads row*64B + quad*16B -> conflict-free.
// + bias + RoPE + scatter; V stored transposed (B,H,DK,S).
// ---------------------------------------------------------------------------
__global__ __launch_bounds__(256) void qkv_gemm_kernel(
    const short* __restrict__ xb, const short* __restrict__ Wt,
    const float* __restrict__ bias,
    short* __restrict__ qd, short* __restrict__ kd, short* __restrict__ vtb)
{
    __shared__ __align__(16) short As[128 * 32];   // [row][32 shorts]
    __shared__ __align__(16) short Bs[128 * 32];
    const int tid = threadIdx.x;
    const int lane = tid & 63, wave = tid >> 6;
    const int wm = wave & 1, wn = wave >> 1;
    const int l15 = lane & 15, quad = lane >> 4;
    const int n0 = blockIdx.x * 128, m0 = blockIdx.y * 128;
    const int srow = lane >> 2, sc = lane & 3;

    // wave w stages rows [w*32, w*32+32) of each matrix (2 instrs x 16 rows)
    const short* gA1 = xb + (size_t)(m0 + wave * 32 + srow) * DMODEL + sc * 8;
    const short* gA2 = gA1 + (size_t)16 * DMODEL;
    const short* gB1 = Wt + (size_t)(n0 + wave * 32 + srow) * DMODEL + sc * 8;
    const short* gB2 = gB1 + (size_t)16 * DMODEL;
    short* lA1 = As + (wave * 32) * 32;
    short* lA2 = As + (wave * 32 + 16) * 32;
    short* lB1 = Bs + (wave * 32) * 32;
    short* lB2 = Bs + (wave * 32 + 16) * 32;

    f32x4 zero = {0.f, 0.f, 0.f, 0.f};
    f32x4 acc[4][4];
    #pragma unroll
    for (int i = 0; i < 4; ++i)
        #pragma unroll
        for (int j = 0; j < 4; ++j) acc[i][j] = zero;

    for (int k0 = 0; k0 < DMODEL; k0 += 32) {
        __syncthreads();                  // prior frag reads done
        gld_lds16(gA1 + k0, lA1);
        gld_lds16(gA2 + k0, lA2);
        gld_lds16(gB1 + k0, lB1);
        gld_lds16(gB2 + k0, lB2);
        __syncthreads();                  // tiles landed (compiler drains vmcnt)
        bf16x8 af[4], bfr[4];
        #pragma unroll
        for (int i = 0; i < 4; ++i)
            af[i] = *(const bf16x8*)&As[(wm * 64 + i * 16 + l15) * 32 + quad * 8];
        #pragma unroll
        for (int j = 0; j < 4; ++j)
            bfr[j] = *(const bf16x8*)&Bs[(wn * 64 + j * 16 + l15) * 32 + quad * 8];
        #pragma unroll
        for (int i = 0; i < 4; ++i)
            #pragma unroll
            for (int j = 0; j < 4; ++j)
                acc[i][j] = __builtin_amdgcn_mfma_f32_16x16x32_bf16(af[i], bfr[j], acc[i][j], 0, 0, 0);
    }

    const int which = n0 >> 10;
    float biasv[4], invf[4];
    int hh[4], dd[4];
    #pragma unroll
    for (int j = 0; j < 4; ++j) {
        const int n = n0 + wn * 64 + j * 16 + l15;
        biasv[j] = bias[n];
        hh[j] = (n & 1023) >> 6;
        dd[j] = n & 63;
        invf[j] = INV2PI * exp2f(-((float)(dd[j] & ~1) / 64.f) * LOG2_10000);
    }
    #pragma unroll
    for (int i = 0; i < 4; ++i) {
        #pragma unroll
        for (int r = 0; r < 4; ++r) {
            const int m = m0 + wm * 64 + i * 16 + quad * 4 + r;
            const int b = m >> 11, t = m & (SEQ - 1);
            #pragma unroll
            for (int j = 0; j < 4; ++j) {
                float val = acc[i][j][r] + biasv[j];
                if (which < 2) {
                    const float rev = (float)t * invf[j];
                    const float fr = rev - floorf(rev);
                    const float s = __builtin_amdgcn_sinf(fr);
                    const float c = __builtin_amdgcn_cosf(fr);
                    const float partner = __shfl_xor(val, 1);
                    val = (lane & 1) ? (partner * s + val * c) : (val * c - partner * s);
                    short* dst = (which == 0) ? qd : kd;
                    dst[((size_t)(b * NHEAD + hh[j]) * SEQ + t) * HDK + dd[j]] = f2bf(val);
                } else {
                    vtb[((size_t)(b * NHEAD + hh[j]) * HDK + dd[j]) * SEQ + t] = f2bf(val);
                }
            }
        }
    }
}

// ---------------------------------------------------------------------------
// Flash attention (MFMA bf16), paired Q-tiles (i, 31-i), fixed softmax max,
// register-prefetched K/V staging. K/V tiles as lo/hi half-tiles [64][32]
// (64B rows): lane-consecutive writes (conflict-free) + conflict-free reads.
// grid (16, NHEAD, BATCH), 256 thr = 4 waves.
// ---------------------------------------------------------------------------
__global__ __launch_bounds__(256) void attn_mfma_kernel(
    const short* __restrict__ qd, const short* __restrict__ kd,
    const short* __restrict__ vt, short* __restrict__ od)
{
    __shared__ __align__(16) short Ks0[64 * 32];   // K cols 0-31
    __shared__ __align__(16) short Ks1[64 * 32];   // K cols 32-63
    __shared__ __align__(16) short Vs0[64 * 32];   // Vt[d][s] s-cols 0-31 of tile
    __shared__ __align__(16) short Vs1[64 * 32];   // s-cols 32-63
    __shared__ __align__(16) short Ps[4][16][72];  // per-wave P tile
    const int tid = threadIdx.x, lane = tid & 63, w = tid >> 6;
    const int l15 = lane & 15, quad = lane >> 4;
    const int h = blockIdx.y, b = blockIdx.z;
    const size_t base = ((size_t)(b * NHEAD + h)) * SEQ * HDK;
    const int srow = tid >> 2, sc = tid & 3;       // srow 0..63, sc 0..3
    const int lofs = srow * 32 + sc * 8;           // = tid*8 (lane-consecutive)
    f32x4 zero = {0.f, 0.f, 0.f, 0.f};

    const int qtile[2] = { (int)blockIdx.x, 31 - (int)blockIdx.x };
    const short* kp = kd + base + (size_t)srow * HDK + sc * 8;   // tile 0
    const short* vp = vt + base + (size_t)srow * SEQ + sc * 8;

    #pragma unroll 1
    for (int qi = 0; qi < 2; ++qi) {
        const int q0 = qtile[qi] * 64;
        bf16x8 qf[2];
        {
            const short* qrow = qd + base + (size_t)(q0 + w * 16 + l15) * HDK;
            qf[0] = *(const bf16x8*)(qrow + quad * 8);
            qf[1] = *(const bf16x8*)(qrow + 32 + quad * 8);
        }
        float l_acc[4] = {0.f, 0.f, 0.f, 0.f};
        f32x4 o[4];
        #pragma unroll
        for (int j = 0; j < 4; ++j) o[j] = zero;

        // preload tile 0 of this q-tile pass (lo = 16B, hi = +64B within row)
        bf16x8 k0v = *(const bf16x8*)kp, k1v = *(const bf16x8*)(kp + 32);
        bf16x8 v0v = *(const bf16x8*)vp, v1v = *(const bf16x8*)(vp + 32);

        const int nkt = q0 / 64 + 1;
        for (int kt = 0; kt < nkt; ++kt) {
            __syncthreads();              // prev compute done with Ks/Vs
            *(bf16x8*)&Ks0[lofs] = k0v; *(bf16x8*)&Ks1[lofs] = k1v;
            *(bf16x8*)&Vs0[lofs] = v0v; *(bf16x8*)&Vs1[lofs] = v1v;
            __syncthreads();
            // issue next tile's loads NOW so latency overlaps compute
            if (kt + 1 < nkt) {
                const short* kn = kd + base + (size_t)((kt + 1) * 64 + srow) * HDK + sc * 8;
                const short* vn = vt + base + (size_t)srow * SEQ + (kt + 1) * 64 + sc * 8;
                k0v = *(const bf16x8*)kn; k1v = *(const bf16x8*)(kn + 32);
                v0v = *(const bf16x8*)vn; v1v = *(const bf16x8*)(vn + 32);
            } else if (qi == 0) {
                k0v = *(const bf16x8*)kp; k1v = *(const bf16x8*)(kp + 32);
                v0v = *(const bf16x8*)vp; v1v = *(const bf16x8*)(vp + 32);
            }

            f32x4 sacc[4];
            #pragma unroll
            for (int j = 0; j < 4; ++j) {
                bf16x8 kf0 = *(const bf16x8*)&Ks0[(j * 16 + l15) * 32 + quad * 8];
                bf16x8 kf1 = *(const bf16x8*)&Ks1[(j * 16 + l15) * 32 + quad * 8];
                sacc[j] = __builtin_amdgcn_mfma_f32_16x16x32_bf16(qf[0], kf0, zero, 0, 0, 0);
                sacc[j] = __builtin_amdgcn_mfma_f32_16x16x32_bf16(qf[1], kf1, sacc[j], 0, 0, 0);
            }
            if (kt == nkt - 1) {                   // diagonal tile: mask
                const int s0 = kt * 64;
                #pragma unroll
                for (int j = 0; j < 4; ++j) {
                    const int scol = s0 + j * 16 + l15;
                    #pragma unroll
                    for (int r = 0; r < 4; ++r) {
                        const int trow = q0 + w * 16 + quad * 4 + r;
                        const float sv = sacc[j][r] * SCALE_LOG2E - M_FIX;
                        const float p = (scol > trow) ? 0.f : fast_exp2(sv);
                        l_acc[r] += p;
                        Ps[w][quad * 4 + r][j * 16 + l15] = f2bf(p);
                    }
                }
            } else {
                #pragma unroll
                for (int j = 0; j < 4; ++j)
                    #pragma unroll
                    for (int r = 0; r < 4; ++r) {
                        const float p = fast_exp2(sacc[j][r] * SCALE_LOG2E - M_FIX);
                        l_acc[r] += p;
                        Ps[w][quad * 4 + r][j * 16 + l15] = f2bf(p);
                    }
            }
            bf16x8 pf0 = *(const bf16x8*)&Ps[w][l15][quad * 8];
            bf16x8 pf1 = *(const bf16x8*)&Ps[w][l15][32 + quad * 8];
            #pragma unroll
            for (int j = 0; j < 4; ++j) {
                bf16x8 vf0 = *(const bf16x8*)&Vs0[(j * 16 + l15) * 32 + quad * 8];
                bf16x8 vf1 = *(const bf16x8*)&Vs1[(j * 16 + l15) * 32 + quad * 8];
                o[j] = __builtin_amdgcn_mfma_f32_16x16x32_bf16(pf0, vf0, o[j], 0, 0, 0);
                o[j] = __builtin_amdgcn_mfma_f32_16x16x32_bf16(pf1, vf1, o[j], 0, 0, 0);
            }
        }

        #pragma unroll
        for (int r = 0; r < 4; ++r) {
            float sr = l_acc[r];
            #pragma unroll
            for (int off = 1; off < 16; off <<= 1) sr += __shfl_xor(sr, off);
            l_acc[r] = sr;
        }
        #pragma unroll
        for (int r = 0; r < 4; ++r) {
            const float inv = 1.f / l_acc[r];
            const int t = q0 + w * 16 + quad * 4 + r;
            #pragma unroll
            for (int j = 0; j < 4; ++j)
                od[((size_t)(b * SEQ + t) * NHEAD + h) * HDK + j * 16 + l15] =
                    f2bf(o[j][r] * inv);
        }
    }
}

// ---------------------------------------------------------------------------
// Output GEMM (row-major LDS staging, same as qkv): out = attn @ W_out + b
// ---------------------------------------------------------------------------
__global__ __launch_bounds__(256) void out_gemm_kernel(
    const short* __restrict__ Ab, const short* __restrict__ Wt,
    const float* __restrict__ bias, float* __restrict__ out)
{
    __shared__ __align__(16) short As[128 * 32];
    __shared__ __align__(16) short Bs[128 * 32];
    const int tid = threadIdx.x;
    const int lane = tid & 63, wave = tid >> 6;
    const int wm = wave & 1, wn = wave >> 1;
    const int l15 = lane & 15, quad = lane >> 4;
    const int n0 = blockIdx.x * 128, m0 = blockIdx.y * 128;
    const int srow = lane >> 2, sc = lane & 3;

    const short* gA1 = Ab + (size_t)(m0 + wave * 32 + srow) * DMODEL + sc * 8;
    const short* gA2 = gA1 + (size_t)16 * DMODEL;
    const short* gB1 = Wt + (size_t)(n0 + wave * 32 + srow) * DMODEL + sc * 8;
    const short* gB2 = gB1 + (size_t)16 * DMODEL;
    short* lA1 = As + (wave * 32) * 32;
    short* lA2 = As + (wave * 32 + 16) * 32;
    short* lB1 = Bs + (wave * 32) * 32;
    short* lB2 = Bs + (wave * 32 + 16) * 32;

    f32x4 zero = {0.f, 0.f, 0.f, 0.f};
    f32x4 acc[4][4];
    #pragma unroll
    for (int i = 0; i < 4; ++i)
        #pragma unroll
        for (int j = 0; j < 4; ++j) acc[i][j] = zero;

    for (int k0 = 0; k0 < DMODEL; k0 += 32) {
        __syncthreads();
        gld_lds16(gA1 + k0, lA1);
        gld_lds16(gA2 + k0, lA2);
        gld_lds16(gB1 + k0, lB1);
        gld_lds16(gB2 + k0, lB2);
        __syncthreads();
        bf16x8 af[4], bfr[4];
        #pragma unroll
        for (int i = 0; i < 4; ++i)
            af[i] = *(const bf16x8*)&As[(wm * 64 + i * 16 + l15) * 32 + quad * 8];
        #pragma unroll
        for (int j = 0; j < 4; ++j)
            bfr[j] = *(const bf16x8*)&Bs[(wn * 64 + j * 16 + l15) * 32 + quad * 8];
        #pragma unroll
        for (int i = 0; i < 4; ++i)
            #pragma unroll
            for (int j = 0; j < 4; ++j)
                acc[i][j] = __builtin_amdgcn_mfma_f32_16x16x32_bf16(af[i], bfr[j], acc[i][j], 0, 0, 0);
    }

    #pragma unroll
    for (int j = 0; j < 4; ++j) {
        const int n = n0 + wn * 64 + j * 16 + l15;
        const float bv = bias[n];
        #pragma unroll
        for (int i = 0; i < 4; ++i)
            #pragma unroll
            for (int r = 0; r < 4; ++r) {
                const int m = m0 + wm * 64 + i * 16 + quad * 4 + r;
                out[(size_t)m * DMODEL + n] = acc[i][j][r] + bv;
            }
    }
}

// ---------------------------------------------------------------------------
extern "C" void kernel_launch(void* const* d_in, const int* in_sizes, int n_in,
                              void* d_out, int out_size, void* d_ws, size_t ws_size,
                              hipStream_t stream) {
    const float* x    = (const float*)d_in[0];
    const float* Wqkv = (const float*)d_in[1];
    const float* bqkv = (const float*)d_in[2];
    const float* Wout = (const float*)d_in[3];
    const float* bout = (const float*)d_in[4];
    float* out = (float*)d_out;

    short* ws = (short*)d_ws;
    short* xb     = ws;                                // 4M elems
    short* wqkv_t = xb + (size_t)4 * 1024 * 1024;      // 3M
    short* wout_t = wqkv_t + (size_t)3 * 1024 * 1024;  // 1M
    short* qd     = wout_t + (size_t)1024 * 1024;      // 4M
    short* kd     = qd + (size_t)4 * 1024 * 1024;      // 4M
    short* vtb    = kd + (size_t)4 * 1024 * 1024;      // 4M (transposed V)
    short* attn   = vtb + (size_t)4 * 1024 * 1024;     // 4M  (total 48 MB)

    convert_kernel<<<(MROWS * DMODEL) / (256 * 8), 256, 0, stream>>>(
        x, xb, MROWS * DMODEL);
    transpose_both_kernel<<<dim3(96 + 32, 32), dim3(32, 8), 0, stream>>>(
        Wqkv, Wout, wqkv_t, wout_t);

    qkv_gemm_kernel<<<dim3(NQKV / 128, MROWS / 128), 256, 0, stream>>>(
        xb, wqkv_t, bqkv, qd, kd, vtb);

    attn_mfma_kernel<<<dim3(16, NHEAD, BATCH), 256, 0, stream>>>(
        qd, kd, vtb, attn);

    out_gemm_kernel<<<dim3(DMODEL / 128, MROWS / 128), 256, 0, stream>>>(
        attn, wout_t, bout, out);
}

// Round 8
// 196.005 us; speedup vs baseline: 1.2587x; 1.0093x over previous
//
#include <hip/hip_runtime.h>
#include <math.h>

#define DMODEL 1024
#define NHEAD  16
#define HDK    64
#define BATCH  2
#define SEQ    2048
#define MROWS  (BATCH*SEQ)   // 4096
#define NQKV   (3*DMODEL)    // 3072
#define LOG2_10000 13.287712379549449f
#define INV2PI 0.15915494309189535f
#define SCALE_LOG2E 0.1803368801111137f   // 0.125 * log2(e)
#define M_FIX 8.0f                        // fixed softmax max (log2 domain)

typedef __attribute__((ext_vector_type(8))) short bf16x8;
typedef __attribute__((ext_vector_type(4))) float f32x4;

__device__ __forceinline__ short f2bf(float f) {
    union { float f; unsigned u; } v; v.f = f;
    unsigned r = v.u + 0x7fffu + ((v.u >> 16) & 1u);
    return (short)(r >> 16);
}

__device__ __forceinline__ float fast_exp2(float x) {
#if __has_builtin(__builtin_amdgcn_exp2f)
    return __builtin_amdgcn_exp2f(x);
#else
    return exp2f(x);
#endif
}

// async global->LDS, 16B per lane; LDS base wave-uniform, HW adds lane*16
__device__ __forceinline__ void gld_lds16(const short* g, short* l) {
    __builtin_amdgcn_global_load_lds(
        (const __attribute__((address_space(1))) void*)g,
        (__attribute__((address_space(3))) void*)l, 16, 0, 0);
}

// ---------------------------------------------------------------------------
// Prep: x fp32->bf16 (blocks 0..2047) + both weights transposed to (N,K) bf16
// (blocks 2048..6143). One launch instead of two.
// ---------------------------------------------------------------------------
__global__ __launch_bounds__(256) void prep_kernel(
    const float* __restrict__ x, const float* __restrict__ wqkv,
    const float* __restrict__ wout,
    short* __restrict__ xb, short* __restrict__ wqkv_t, short* __restrict__ wout_t)
{
    __shared__ short tile[32][33];
    const int tid = threadIdx.x;
    if (blockIdx.x < 2048) {
        const int i = (blockIdx.x * 256 + tid) * 8;
        float4 a = *(const float4*)(x + i);
        float4 b = *(const float4*)(x + i + 4);
        bf16x8 o;
        o[0] = f2bf(a.x); o[1] = f2bf(a.y); o[2] = f2bf(a.z); o[3] = f2bf(a.w);
        o[4] = f2bf(b.x); o[5] = f2bf(b.y); o[6] = f2bf(b.z); o[7] = f2bf(b.w);
        *(bf16x8*)(xb + i) = o;
        return;
    }
    const int bx = blockIdx.x - 2048;
    int nx = bx & 127;
    const int ky = bx >> 7;
    const float* in; short* out; int N;
    if (nx < 96) { in = wqkv; out = wqkv_t; N = NQKV; }
    else         { in = wout; out = wout_t; N = DMODEL; nx -= 96; }
    const int tx = tid & 31, ty = tid >> 5;
    const int n0 = nx * 32, k0 = ky * 32;
    #pragma unroll
    for (int i = 0; i < 32; i += 8)
        tile[ty + i][tx] = f2bf(in[(size_t)(k0 + ty + i) * N + n0 + tx]);
    __syncthreads();
    #pragma unroll
    for (int i = 0; i < 32; i += 8)
        out[(size_t)(n0 + ty + i) * DMODEL + k0 + tx] = tile[tx][ty + i];
}

// ---------------------------------------------------------------------------
// QKV GEMM (MFMA bf16, global_load_lds, row-major LDS [128][32]).
// + bias + RoPE + scatter; V stored transposed (B,H,DK,S).
// ---------------------------------------------------------------------------
__global__ __launch_bounds__(256) void qkv_gemm_kernel(
    const short* __restrict__ xb, const short* __restrict__ Wt,
    const float* __restrict__ bias,
    short* __restrict__ qd, short* __restrict__ kd, short* __restrict__ vtb)
{
    __shared__ __align__(16) short As[128 * 32];
    __shared__ __align__(16) short Bs[128 * 32];
    const int tid = threadIdx.x;
    const int lane = tid & 63, wave = tid >> 6;
    const int wm = wave & 1, wn = wave >> 1;
    const int l15 = lane & 15, quad = lane >> 4;
    const int n0 = blockIdx.x * 128, m0 = blockIdx.y * 128;
    const int srow = lane >> 2, sc = lane & 3;

    const short* gA1 = xb + (size_t)(m0 + wave * 32 + srow) * DMODEL + sc * 8;
    const short* gA2 = gA1 + (size_t)16 * DMODEL;
    const short* gB1 = Wt + (size_t)(n0 + wave * 32 + srow) * DMODEL + sc * 8;
    const short* gB2 = gB1 + (size_t)16 * DMODEL;
    short* lA1 = As + (wave * 32) * 32;
    short* lA2 = As + (wave * 32 + 16) * 32;
    short* lB1 = Bs + (wave * 32) * 32;
    short* lB2 = Bs + (wave * 32 + 16) * 32;

    f32x4 zero = {0.f, 0.f, 0.f, 0.f};
    f32x4 acc[4][4];
    #pragma unroll
    for (int i = 0; i < 4; ++i)
        #pragma unroll
        for (int j = 0; j < 4; ++j) acc[i][j] = zero;

    for (int k0 = 0; k0 < DMODEL; k0 += 32) {
        __syncthreads();
        gld_lds16(gA1 + k0, lA1);
        gld_lds16(gA2 + k0, lA2);
        gld_lds16(gB1 + k0, lB1);
        gld_lds16(gB2 + k0, lB2);
        __syncthreads();
        bf16x8 af[4], bfr[4];
        #pragma unroll
        for (int i = 0; i < 4; ++i)
            af[i] = *(const bf16x8*)&As[(wm * 64 + i * 16 + l15) * 32 + quad * 8];
        #pragma unroll
        for (int j = 0; j < 4; ++j)
            bfr[j] = *(const bf16x8*)&Bs[(wn * 64 + j * 16 + l15) * 32 + quad * 8];
        #pragma unroll
        for (int i = 0; i < 4; ++i)
            #pragma unroll
            for (int j = 0; j < 4; ++j)
                acc[i][j] = __builtin_amdgcn_mfma_f32_16x16x32_bf16(af[i], bfr[j], acc[i][j], 0, 0, 0);
    }

    const int which = n0 >> 10;
    float biasv[4], invf[4];
    int hh[4], dd[4];
    #pragma unroll
    for (int j = 0; j < 4; ++j) {
        const int n = n0 + wn * 64 + j * 16 + l15;
        biasv[j] = bias[n];
        hh[j] = (n & 1023) >> 6;
        dd[j] = n & 63;
        invf[j] = INV2PI * exp2f(-((float)(dd[j] & ~1) / 64.f) * LOG2_10000);
    }
    #pragma unroll
    for (int i = 0; i < 4; ++i) {
        #pragma unroll
        for (int r = 0; r < 4; ++r) {
            const int m = m0 + wm * 64 + i * 16 + quad * 4 + r;
            const int b = m >> 11, t = m & (SEQ - 1);
            #pragma unroll
            for (int j = 0; j < 4; ++j) {
                float val = acc[i][j][r] + biasv[j];
                if (which < 2) {
                    const float rev = (float)t * invf[j];
                    const float fr = rev - floorf(rev);
                    const float s = __builtin_amdgcn_sinf(fr);
                    const float c = __builtin_amdgcn_cosf(fr);
                    const float partner = __shfl_xor(val, 1);
                    val = (lane & 1) ? (partner * s + val * c) : (val * c - partner * s);
                    short* dst = (which == 0) ? qd : kd;
                    dst[((size_t)(b * NHEAD + hh[j]) * SEQ + t) * HDK + dd[j]] = f2bf(val);
                } else {
                    vtb[((size_t)(b * NHEAD + hh[j]) * HDK + dd[j]) * SEQ + t] = f2bf(val);
                }
            }
        }
    }
}

// ---------------------------------------------------------------------------
// Flash attention (MFMA bf16). XCD-swizzled 1-D grid (512 blocks): all blocks
// of one (b,h) share id%8 -> same XCD -> K/V stay in that XCD's L2.
// Paired Q-tiles (i,31-i); fixed softmax max; register-prefetched staging;
// TWO 64-row s-tiles staged per barrier pair.
// ---------------------------------------------------------------------------
__global__ __launch_bounds__(256) void attn_mfma_kernel(
    const short* __restrict__ qd, const short* __restrict__ kd,
    const short* __restrict__ vt, short* __restrict__ od)
{
    __shared__ __align__(16) short Ks[2][2][64 * 32];  // [tile][half][row*32]
    __shared__ __align__(16) short Vs[2][2][64 * 32];  // Vt halves
    __shared__ __align__(16) short Ps[4][16][72];      // per-wave P tile
    const int tid = threadIdx.x, lane = tid & 63, w = tid >> 6;
    const int l15 = lane & 15, quad = lane >> 4;
    // XCD swizzle: c = id%8 is the XCD slot; hb = c + 8*(id>>7)
    const int id = (int)blockIdx.x;
    const int c = id & 7, kk = id >> 3;
    const int qp = kk & 15, jj = kk >> 4;
    const int hb = c + 8 * jj;
    const int h = hb & 15, b = hb >> 4;
    const size_t base = ((size_t)(b * NHEAD + h)) * SEQ * HDK;
    const int srow = tid >> 2, sc = tid & 3;
    const int lofs = tid * 8;
    f32x4 zero = {0.f, 0.f, 0.f, 0.f};

    const int qtile[2] = { qp, 31 - qp };
    const short* kp0 = kd + base + (size_t)srow * HDK + sc * 8;
    const short* vp0 = vt + base + (size_t)srow * SEQ + sc * 8;
    const short* kp1 = kp0 + (size_t)64 * HDK;
    const short* vp1 = vp0 + 64;

    #pragma unroll 1
    for (int qi = 0; qi < 2; ++qi) {
        const int q0 = qtile[qi] * 64;
        bf16x8 qf[2];
        {
            const short* qrow = qd + base + (size_t)(q0 + w * 16 + l15) * HDK;
            qf[0] = *(const bf16x8*)(qrow + quad * 8);
            qf[1] = *(const bf16x8*)(qrow + 32 + quad * 8);
        }
        float l_acc[4] = {0.f, 0.f, 0.f, 0.f};
        f32x4 o[4];
        #pragma unroll
        for (int j = 0; j < 4; ++j) o[j] = zero;

        const int nkt = q0 / 64 + 1;
        const int npair = (nkt + 1) >> 1;

        // preload pair 0 (tile 1 is memory-safe even when nkt==1)
        bf16x8 rk[2][2], rv[2][2];
        rk[0][0] = *(const bf16x8*)kp0; rk[0][1] = *(const bf16x8*)(kp0 + 32);
        rv[0][0] = *(const bf16x8*)vp0; rv[0][1] = *(const bf16x8*)(vp0 + 32);
        rk[1][0] = *(const bf16x8*)kp1; rk[1][1] = *(const bf16x8*)(kp1 + 32);
        rv[1][0] = *(const bf16x8*)vp1; rv[1][1] = *(const bf16x8*)(vp1 + 32);

        for (int p = 0; p < npair; ++p) {
            __syncthreads();              // prev compute done with Ks/Vs
            *(bf16x8*)&Ks[0][0][lofs] = rk[0][0]; *(bf16x8*)&Ks[0][1][lofs] = rk[0][1];
            *(bf16x8*)&Vs[0][0][lofs] = rv[0][0]; *(bf16x8*)&Vs[0][1][lofs] = rv[0][1];
            *(bf16x8*)&Ks[1][0][lofs] = rk[1][0]; *(bf16x8*)&Ks[1][1][lofs] = rk[1][1];
            *(bf16x8*)&Vs[1][0][lofs] = rv[1][0]; *(bf16x8*)&Vs[1][1][lofs] = rv[1][1];
            __syncthreads();
            // prefetch next pair (overlaps with compute below)
            if (p + 1 < npair) {
                const int sn = (2 * p + 2) * 64;
                const short* kn = kd + base + (size_t)(sn + srow) * HDK + sc * 8;
                const short* vn = vt + base + (size_t)srow * SEQ + sn + sc * 8;
                rk[0][0] = *(const bf16x8*)kn; rk[0][1] = *(const bf16x8*)(kn + 32);
                rv[0][0] = *(const bf16x8*)vn; rv[0][1] = *(const bf16x8*)(vn + 32);
                const short* kn2 = kn + (size_t)64 * HDK;
                const short* vn2 = vn + 64;
                rk[1][0] = *(const bf16x8*)kn2; rk[1][1] = *(const bf16x8*)(kn2 + 32);
                rv[1][0] = *(const bf16x8*)vn2; rv[1][1] = *(const bf16x8*)(vn2 + 32);
            } else if (qi == 0) {
                rk[0][0] = *(const bf16x8*)kp0; rk[0][1] = *(const bf16x8*)(kp0 + 32);
                rv[0][0] = *(const bf16x8*)vp0; rv[0][1] = *(const bf16x8*)(vp0 + 32);
                rk[1][0] = *(const bf16x8*)kp1; rk[1][1] = *(const bf16x8*)(kp1 + 32);
                rv[1][0] = *(const bf16x8*)vp1; rv[1][1] = *(const bf16x8*)(vp1 + 32);
            }

            #pragma unroll
            for (int tt = 0; tt < 2; ++tt) {
                const int kt = 2 * p + tt;
                if (tt == 1 && kt >= nkt) break;    // uniform across block
                f32x4 sacc[4];
                #pragma unroll
                for (int j = 0; j < 4; ++j) {
                    bf16x8 kf0 = *(const bf16x8*)&Ks[tt][0][(j * 16 + l15) * 32 + quad * 8];
                    bf16x8 kf1 = *(const bf16x8*)&Ks[tt][1][(j * 16 + l15) * 32 + quad * 8];
                    sacc[j] = __builtin_amdgcn_mfma_f32_16x16x32_bf16(qf[0], kf0, zero, 0, 0, 0);
                    sacc[j] = __builtin_amdgcn_mfma_f32_16x16x32_bf16(qf[1], kf1, sacc[j], 0, 0, 0);
                }
                if (kt == nkt - 1) {                // diagonal tile: mask
                    const int s0 = kt * 64;
                    #pragma unroll
                    for (int j = 0; j < 4; ++j) {
                        const int scol = s0 + j * 16 + l15;
                        #pragma unroll
                        for (int r = 0; r < 4; ++r) {
                            const int trow = q0 + w * 16 + quad * 4 + r;
                            const float sv = sacc[j][r] * SCALE_LOG2E - M_FIX;
                            const float pv = (scol > trow) ? 0.f : fast_exp2(sv);
                            l_acc[r] += pv;
                            Ps[w][quad * 4 + r][j * 16 + l15] = f2bf(pv);
                        }
                    }
                } else {
                    #pragma unroll
                    for (int j = 0; j < 4; ++j)
                        #pragma unroll
                        for (int r = 0; r < 4; ++r) {
                            const float pv = fast_exp2(sacc[j][r] * SCALE_LOG2E - M_FIX);
                            l_acc[r] += pv;
                            Ps[w][quad * 4 + r][j * 16 + l15] = f2bf(pv);
                        }
                }
                bf16x8 pf0 = *(const bf16x8*)&Ps[w][l15][quad * 8];
                bf16x8 pf1 = *(const bf16x8*)&Ps[w][l15][32 + quad * 8];
                #pragma unroll
                for (int j = 0; j < 4; ++j) {
                    bf16x8 vf0 = *(const bf16x8*)&Vs[tt][0][(j * 16 + l15) * 32 + quad * 8];
                    bf16x8 vf1 = *(const bf16x8*)&Vs[tt][1][(j * 16 + l15) * 32 + quad * 8];
                    o[j] = __builtin_amdgcn_mfma_f32_16x16x32_bf16(pf0, vf0, o[j], 0, 0, 0);
                    o[j] = __builtin_amdgcn_mfma_f32_16x16x32_bf16(pf1, vf1, o[j], 0, 0, 0);
                }
            }
        }

        #pragma unroll
        for (int r = 0; r < 4; ++r) {
            float sr = l_acc[r];
            #pragma unroll
            for (int off = 1; off < 16; off <<= 1) sr += __shfl_xor(sr, off);
            l_acc[r] = sr;
        }
        #pragma unroll
        for (int r = 0; r < 4; ++r) {
            const float inv = 1.f / l_acc[r];
            const int t = q0 + w * 16 + quad * 4 + r;
            #pragma unroll
            for (int j = 0; j < 4; ++j)
                od[((size_t)(b * SEQ + t) * NHEAD + h) * HDK + j * 16 + l15] =
                    f2bf(o[j][r] * inv);
        }
    }
}

// ---------------------------------------------------------------------------
// Output GEMM (row-major LDS staging): out = attn @ W_out + b (fp32)
// ---------------------------------------------------------------------------
__global__ __launch_bounds__(256) void out_gemm_kernel(
    const short* __restrict__ Ab, const short* __restrict__ Wt,
    const float* __restrict__ bias, float* __restrict__ out)
{
    __shared__ __align__(16) short As[128 * 32];
    __shared__ __align__(16) short Bs[128 * 32];
    const int tid = threadIdx.x;
    const int lane = tid & 63, wave = tid >> 6;
    const int wm = wave & 1, wn = wave >> 1;
    const int l15 = lane & 15, quad = lane >> 4;
    const int n0 = blockIdx.x * 128, m0 = blockIdx.y * 128;
    const int srow = lane >> 2, sc = lane & 3;

    const short* gA1 = Ab + (size_t)(m0 + wave * 32 + srow) * DMODEL + sc * 8;
    const short* gA2 = gA1 + (size_t)16 * DMODEL;
    const short* gB1 = Wt + (size_t)(n0 + wave * 32 + srow) * DMODEL + sc * 8;
    const short* gB2 = gB1 + (size_t)16 * DMODEL;
    short* lA1 = As + (wave * 32) * 32;
    short* lA2 = As + (wave * 32 + 16) * 32;
    short* lB1 = Bs + (wave * 32) * 32;
    short* lB2 = Bs + (wave * 32 + 16) * 32;

    f32x4 zero = {0.f, 0.f, 0.f, 0.f};
    f32x4 acc[4][4];
    #pragma unroll
    for (int i = 0; i < 4; ++i)
        #pragma unroll
        for (int j = 0; j < 4; ++j) acc[i][j] = zero;

    for (int k0 = 0; k0 < DMODEL; k0 += 32) {
        __syncthreads();
        gld_lds16(gA1 + k0, lA1);
        gld_lds16(gA2 + k0, lA2);
        gld_lds16(gB1 + k0, lB1);
        gld_lds16(gB2 + k0, lB2);
        __syncthreads();
        bf16x8 af[4], bfr[4];
        #pragma unroll
        for (int i = 0; i < 4; ++i)
            af[i] = *(const bf16x8*)&As[(wm * 64 + i * 16 + l15) * 32 + quad * 8];
        #pragma unroll
        for (int j = 0; j < 4; ++j)
            bfr[j] = *(const bf16x8*)&Bs[(wn * 64 + j * 16 + l15) * 32 + quad * 8];
        #pragma unroll
        for (int i = 0; i < 4; ++i)
            #pragma unroll
            for (int j = 0; j < 4; ++j)
                acc[i][j] = __builtin_amdgcn_mfma_f32_16x16x32_bf16(af[i], bfr[j], acc[i][j], 0, 0, 0);
    }

    #pragma unroll
    for (int j = 0; j < 4; ++j) {
        const int n = n0 + wn * 64 + j * 16 + l15;
        const float bv = bias[n];
        #pragma unroll
        for (int i = 0; i < 4; ++i)
            #pragma unroll
            for (int r = 0; r < 4; ++r) {
                const int m = m0 + wm * 64 + i * 16 + quad * 4 + r;
                out[(size_t)m * DMODEL + n] = acc[i][j][r] + bv;
            }
    }
}

// ---------------------------------------------------------------------------
extern "C" void kernel_launch(void* const* d_in, const int* in_sizes, int n_in,
                              void* d_out, int out_size, void* d_ws, size_t ws_size,
                              hipStream_t stream) {
    const float* x    = (const float*)d_in[0];
    const float* Wqkv = (const float*)d_in[1];
    const float* bqkv = (const float*)d_in[2];
    const float* Wout = (const float*)d_in[3];
    const float* bout = (const float*)d_in[4];
    float* out = (float*)d_out;

    short* ws = (short*)d_ws;
    short* xb     = ws;                                // 4M elems
    short* wqkv_t = xb + (size_t)4 * 1024 * 1024;      // 3M
    short* wout_t = wqkv_t + (size_t)3 * 1024 * 1024;  // 1M
    short* qd     = wout_t + (size_t)1024 * 1024;      // 4M
    short* kd     = qd + (size_t)4 * 1024 * 1024;      // 4M
    short* vtb    = kd + (size_t)4 * 1024 * 1024;      // 4M (transposed V)
    short* attn   = vtb + (size_t)4 * 1024 * 1024;     // 4M  (total 48 MB)

    prep_kernel<<<2048 + 4096, 256, 0, stream>>>(x, Wqkv, Wout, xb, wqkv_t, wout_t);

    qkv_gemm_kernel<<<dim3(NQKV / 128, MROWS / 128), 256, 0, stream>>>(
        xb, wqkv_t, bqkv, qd, kd, vtb);

    attn_mfma_kernel<<<512, 256, 0, stream>>>(qd, kd, vtb, attn);

    out_gemm_kernel<<<dim3(DMODEL / 128, MROWS / 128), 256, 0, stream>>>(
        attn, wout_t, bout, out);
}